// Round 1
// baseline (645.760 us; speedup 1.0000x reference)
//
#include <hip/hip_runtime.h>
#include <hip/hip_bf16.h>

#define NNODES 16384
#define KNEI 25
#define NREL 3
#define DIM 256
#define OUTD 256
#define NTOTAL 100000

typedef __attribute__((ext_vector_type(8))) short short8;
typedef __attribute__((ext_vector_type(4))) float f32x4;

static __device__ __forceinline__ unsigned short f2bf(float x) {
    union { float f; unsigned u; } v; v.f = x;
    unsigned r = v.u + 0x7fff + ((v.u >> 16) & 1);   // RNE
    return (unsigned short)(r >> 16);
}

// ---------------------------------------------------------------------------
// Kernel 0: fold W_rel/W_self into W_comp.
// M_cat[o][slot*256+d] = sum_j W_comp[o][slot*256+j] * Wslot[j][d]   (bf16 out)
// grid = 4 slots * 32 o-groups (8 rows each) = 128 blocks, 256 threads
// ---------------------------------------------------------------------------
__global__ __launch_bounds__(256) void prep_M(
        const float* __restrict__ W_self,
        const float* __restrict__ W_rel,
        const float* __restrict__ W_comp,
        unsigned short* __restrict__ M) {
    const int slot = blockIdx.x >> 5;          // 0..3
    const int o0   = (blockIdx.x & 31) * 8;    // 8 output rows per block
    const int t    = threadIdx.x;              // d = t
    const float* Wslot = (slot < NREL) ? (W_rel + (size_t)slot * OUTD * DIM)
                                       : W_self;
    float acc[8];
#pragma unroll
    for (int oi = 0; oi < 8; ++oi) acc[oi] = 0.f;
    for (int j = 0; j < 256; ++j) {
        const float wv = Wslot[j * 256 + t];            // coalesced
#pragma unroll
        for (int oi = 0; oi < 8; ++oi)                  // uniform -> s_load
            acc[oi] += W_comp[(size_t)(o0 + oi) * 1024 + slot * 256 + j] * wv;
    }
#pragma unroll
    for (int oi = 0; oi < 8; ++oi)
        M[(size_t)(o0 + oi) * 1024 + slot * 256 + t] = f2bf(acc[oi]);
}

// ---------------------------------------------------------------------------
// Main kernel: 16 nodes per block, 256 threads (4 waves).
// Phase 1: gather + K-mean -> bf16 G[16][1024] in LDS (stride 1032 pad).
// Phase 2: h = relu(G @ M^T) via mfma 16x16x32 bf16; bag-mean(8) epilogue.
// ---------------------------------------------------------------------------
#define GSTRIDE 1032   // 1024 + 8 bf16 pad: breaks 16-way LDS bank conflict

__global__ __launch_bounds__(256, 4) void encoder_main(
        const int*   __restrict__ nodes,
        const int*   __restrict__ neigh_idx,
        const float* __restrict__ table_self,
        const float* __restrict__ tables_to,
        const unsigned short* __restrict__ M,
        float* __restrict__ out) {
    __shared__ unsigned short G[16 * GSTRIDE];   // 33 KB

    const int tid  = threadIdx.x;
    const int wave = tid >> 6;
    const int lane = tid & 63;
    const int n0   = blockIdx.x * 16;

    // ---- Phase 1: gather + mean ----
    {
        const int d4 = lane * 4;                 // dims [d4, d4+4)
        const float invK = 1.0f / (float)KNEI;
#pragma unroll
        for (int i = 0; i < 4; ++i) {
            const int li = wave * 4 + i;         // local node row in G
            const int n  = n0 + li;
#pragma unroll
            for (int r = 0; r < NREL; ++r) {
                const int* idxp = neigh_idx + ((size_t)r * NNODES + n) * KNEI;
                const float* tab = tables_to + (size_t)r * NTOTAL * DIM;
                float4 acc = make_float4(0.f, 0.f, 0.f, 0.f);
#pragma unroll 5
                for (int j = 0; j < KNEI; ++j) {
                    const int idx = idxp[j];
                    const float4 v = *(const float4*)(tab + (size_t)idx * DIM + d4);
                    acc.x += v.x; acc.y += v.y; acc.z += v.z; acc.w += v.w;
                }
                ushort4 pk;
                pk.x = f2bf(acc.x * invK); pk.y = f2bf(acc.y * invK);
                pk.z = f2bf(acc.z * invK); pk.w = f2bf(acc.w * invK);
                *(ushort4*)&G[li * GSTRIDE + r * 256 + d4] = pk;
            }
            {   // self slot (3)
                const int row = nodes[n];
                const float4 v = *(const float4*)(table_self + (size_t)row * DIM + d4);
                ushort4 pk;
                pk.x = f2bf(v.x); pk.y = f2bf(v.y);
                pk.z = f2bf(v.z); pk.w = f2bf(v.w);
                *(ushort4*)&G[li * GSTRIDE + 3 * 256 + d4] = pk;
            }
        }
    }
    __syncthreads();

    // ---- Phase 2: GEMM + relu + bag-mean ----
    // wave w covers output cols [w*64, w*64+64); 4 col-tiles of 16
    const int quad = lane >> 4;
    const int l16  = lane & 15;
    f32x4 acc[4];
#pragma unroll
    for (int ct = 0; ct < 4; ++ct) acc[ct] = (f32x4){0.f, 0.f, 0.f, 0.f};

    for (int k0 = 0; k0 < 1024; k0 += 32) {
        // A frag: A[m=l16][k=k0+quad*8+j]  (16B aligned, 2-way banks only)
        const short8 a = *(const short8*)&G[l16 * GSTRIDE + k0 + quad * 8];
#pragma unroll
        for (int ct = 0; ct < 4; ++ct) {
            const int o = wave * 64 + ct * 16 + l16;   // B col
            const short8 b = *(const short8*)(M + (size_t)o * 1024 + k0 + quad * 8);
            acc[ct] = __builtin_amdgcn_mfma_f32_16x16x32_bf16(a, b, acc[ct], 0, 0, 0);
        }
    }

    // C/D layout: col = l16, row(node) = quad*4 + reg.
    // relu -> sum 4 regs -> + shfl_xor(16) => bag of 8 -> /8
    const size_t orow0 = (size_t)blockIdx.x * 2;
#pragma unroll
    for (int ct = 0; ct < 4; ++ct) {
        float s = fmaxf(acc[ct][0], 0.f) + fmaxf(acc[ct][1], 0.f)
                + fmaxf(acc[ct][2], 0.f) + fmaxf(acc[ct][3], 0.f);
        s += __shfl_xor(s, 16, 64);
        s *= 0.125f;
        const int col = wave * 64 + ct * 16 + l16;
        if (quad == 0)      out[orow0 * 256 + col]       = s;   // nodes 0..7
        else if (quad == 2) out[(orow0 + 1) * 256 + col] = s;   // nodes 8..15
    }
}

extern "C" void kernel_launch(void* const* d_in, const int* in_sizes, int n_in,
                              void* d_out, int out_size, void* d_ws, size_t ws_size,
                              hipStream_t stream) {
    const int*   nodes  = (const int*)  d_in[0];
    const int*   neigh  = (const int*)  d_in[1];
    const float* tself  = (const float*)d_in[2];
    const float* tto    = (const float*)d_in[3];
    const float* wself  = (const float*)d_in[4];
    const float* wrel   = (const float*)d_in[5];
    const float* wcomp  = (const float*)d_in[6];
    float* outp = (float*)d_out;
    unsigned short* M = (unsigned short*)d_ws;   // 256*1024 bf16 = 512 KB

    prep_M<<<128, 256, 0, stream>>>(wself, wrel, wcomp, M);
    encoder_main<<<1024, 256, 0, stream>>>(nodes, neigh, tself, tto, M, outp);
}

// Round 2
// 615.527 us; speedup vs baseline: 1.0491x; 1.0491x over previous
//
#include <hip/hip_runtime.h>
#include <hip/hip_bf16.h>

#define NNODES 16384
#define KNEI 25
#define NREL 3
#define DIM 256
#define OUTD 256
#define NTOTAL 100000

typedef __attribute__((ext_vector_type(8))) short short8;
typedef __attribute__((ext_vector_type(4))) float f32x4;

static __device__ __forceinline__ unsigned short f2bf(float x) {
    union { float f; unsigned u; } v; v.f = x;
    unsigned r = v.u + 0x7fff + ((v.u >> 16) & 1);   // RNE
    return (unsigned short)(r >> 16);
}

// ---------------------------------------------------------------------------
// prep_M: fold W_rel/W_self into W_comp -> bf16 M[256][1024].
// M[o][slot*256+d] = sum_j W_comp[o][slot*256+j] * Wslot[j][d]
// 256 blocks: slot = b>>6 (0..3), o0 = (b&63)*4 (4 rows/block). W_comp rows
// staged in LDS (broadcast reads); j-loop unrolled 8 for 8 loads in flight.
// ---------------------------------------------------------------------------
__global__ __launch_bounds__(256) void prep_M(
        const float* __restrict__ W_self,
        const float* __restrict__ W_rel,
        const float* __restrict__ W_comp,
        unsigned short* __restrict__ M) {
    const int slot = blockIdx.x >> 6;
    const int o0   = (blockIdx.x & 63) * 4;
    const int t    = threadIdx.x;            // d = t
    const float* __restrict__ Wslot = (slot < NREL)
        ? (W_rel + (size_t)slot * OUTD * DIM) : W_self;
    __shared__ float C[4 * 256];
#pragma unroll
    for (int oi = 0; oi < 4; ++oi)
        C[oi * 256 + t] = W_comp[(size_t)(o0 + oi) * 1024 + slot * 256 + t];
    __syncthreads();
    float acc[4] = {0.f, 0.f, 0.f, 0.f};
    for (int j = 0; j < 256; j += 8) {
#pragma unroll
        for (int u = 0; u < 8; ++u) {
            const float wv = Wslot[(size_t)(j + u) * 256 + t];   // coalesced
#pragma unroll
            for (int oi = 0; oi < 4; ++oi)
                acc[oi] += C[oi * 256 + j + u] * wv;             // LDS broadcast
        }
    }
#pragma unroll
    for (int oi = 0; oi < 4; ++oi)
        M[(size_t)(o0 + oi) * 1024 + slot * 256 + t] = f2bf(acc[oi]);
}

// ---------------------------------------------------------------------------
// gather_kernel: relation-phased gather + K-mean -> bf16 G[16384][1024] (ws).
// grid 4096: blocks [r*1024, r*1024+1024) handle relation r (r=3 -> self).
// Co-resident blocks touch ONE 100 MB table -> fits 256 MB L3 -> ~compulsory
// fetch. 25 neighbor loads fully unrolled, 5 accumulators -> deep MLP.
// No LDS -> occupancy is VGPR-limited only.
// ---------------------------------------------------------------------------
__global__ __launch_bounds__(256) void gather_kernel(
        const int*   __restrict__ nodes,
        const int*   __restrict__ neigh_idx,
        const float* __restrict__ table_self,
        const float* __restrict__ tables_to,
        unsigned short* __restrict__ G) {
    const int b    = blockIdx.x;
    const int r    = b >> 10;            // 0..3
    const int blk  = b & 1023;
    const int wave = threadIdx.x >> 6;
    const int lane = threadIdx.x & 63;
    const int d4   = lane * 4;           // dims [d4, d4+4)

    if (r < NREL) {
        const float* __restrict__ tab = tables_to + (size_t)r * NTOTAL * DIM;
        const float invK = 1.0f / (float)KNEI;
#pragma unroll
        for (int i = 0; i < 4; ++i) {
            const int n = blk * 16 + wave * 4 + i;
            const int* idxp = neigh_idx + ((size_t)r * NNODES + n) * KNEI;
            float4 acc[5];
#pragma unroll
            for (int j = 0; j < 5; ++j)
                acc[j] = *(const float4*)(tab + (size_t)idxp[j] * DIM + d4);
#pragma unroll
            for (int g = 1; g < 5; ++g) {
#pragma unroll
                for (int j = 0; j < 5; ++j) {
                    const float4 v =
                        *(const float4*)(tab + (size_t)idxp[g * 5 + j] * DIM + d4);
                    acc[j].x += v.x; acc[j].y += v.y;
                    acc[j].z += v.z; acc[j].w += v.w;
                }
            }
            float4 s;
            s.x = (acc[0].x + acc[1].x) + (acc[2].x + acc[3].x) + acc[4].x;
            s.y = (acc[0].y + acc[1].y) + (acc[2].y + acc[3].y) + acc[4].y;
            s.z = (acc[0].z + acc[1].z) + (acc[2].z + acc[3].z) + acc[4].z;
            s.w = (acc[0].w + acc[1].w) + (acc[2].w + acc[3].w) + acc[4].w;
            ushort4 pk;
            pk.x = f2bf(s.x * invK); pk.y = f2bf(s.y * invK);
            pk.z = f2bf(s.z * invK); pk.w = f2bf(s.w * invK);
            *(ushort4*)(G + (size_t)n * 1024 + r * 256 + d4) = pk;
        }
    } else {
        // self slot (3): plain gather, no mean
#pragma unroll
        for (int i = 0; i < 4; ++i) {
            const int n = blk * 16 + wave * 4 + i;
            const float4 v =
                *(const float4*)(table_self + (size_t)nodes[n] * DIM + d4);
            ushort4 pk;
            pk.x = f2bf(v.x); pk.y = f2bf(v.y);
            pk.z = f2bf(v.z); pk.w = f2bf(v.w);
            *(ushort4*)(G + (size_t)n * 1024 + 3 * 256 + d4) = pk;
        }
    }
}

// ---------------------------------------------------------------------------
// gemm_kernel: per block, 16 nodes. Stage G tile [16][1024] bf16 in LDS
// (coalesced b128 loads), then h = relu(G @ M^T) via mfma 16x16x32 bf16,
// bag-mean(8) epilogue (verified in round 1).
// ---------------------------------------------------------------------------
#define GSTRIDE 1032   // 1024 + 8 bf16 pad

__global__ __launch_bounds__(256, 4) void gemm_kernel(
        const unsigned short* __restrict__ G,
        const unsigned short* __restrict__ M,
        float* __restrict__ out) {
    __shared__ unsigned short A[16 * GSTRIDE];   // 33 KB

    const int t    = threadIdx.x;
    const int wave = t >> 6;
    const int lane = t & 63;
    const int quad = lane >> 4;
    const int l16  = lane & 15;

    // stage 16x1024 bf16 tile, coalesced 16 B per thread per round
    const unsigned short* gsrc = G + (size_t)blockIdx.x * 16 * 1024;
#pragma unroll
    for (int rnd = 0; rnd < 8; ++rnd) {
        const int l   = rnd * 2048 + t * 8;
        const int row = l >> 10;
        const int col = l & 1023;
        *(short8*)&A[row * GSTRIDE + col] = *(const short8*)(gsrc + l);
    }
    __syncthreads();

    f32x4 acc[4];
#pragma unroll
    for (int ct = 0; ct < 4; ++ct) acc[ct] = (f32x4){0.f, 0.f, 0.f, 0.f};

    for (int k0 = 0; k0 < 1024; k0 += 32) {
        const short8 a = *(const short8*)&A[l16 * GSTRIDE + k0 + quad * 8];
#pragma unroll
        for (int ct = 0; ct < 4; ++ct) {
            const int o = wave * 64 + ct * 16 + l16;
            const short8 bfrag =
                *(const short8*)(M + (size_t)o * 1024 + k0 + quad * 8);
            acc[ct] = __builtin_amdgcn_mfma_f32_16x16x32_bf16(a, bfrag, acc[ct], 0, 0, 0);
        }
    }

    // C/D: col = l16, row(node) = quad*4 + reg. relu -> sum 4 regs ->
    // shfl_xor(16) combines quad pairs => bag of 8 -> /8
    const size_t orow0 = (size_t)blockIdx.x * 2;
#pragma unroll
    for (int ct = 0; ct < 4; ++ct) {
        float s = fmaxf(acc[ct][0], 0.f) + fmaxf(acc[ct][1], 0.f)
                + fmaxf(acc[ct][2], 0.f) + fmaxf(acc[ct][3], 0.f);
        s += __shfl_xor(s, 16, 64);
        s *= 0.125f;
        const int col = wave * 64 + ct * 16 + l16;
        if (quad == 0)      out[orow0 * 256 + col]       = s;
        else if (quad == 2) out[(orow0 + 1) * 256 + col] = s;
    }
}

// ---------------------------------------------------------------------------
// Fallback fused kernel (round-1 verified) if ws is too small for G.
// ---------------------------------------------------------------------------
__global__ __launch_bounds__(256, 4) void encoder_main(
        const int*   __restrict__ nodes,
        const int*   __restrict__ neigh_idx,
        const float* __restrict__ table_self,
        const float* __restrict__ tables_to,
        const unsigned short* __restrict__ M,
        float* __restrict__ out) {
    __shared__ unsigned short Gt[16 * GSTRIDE];
    const int tid  = threadIdx.x;
    const int wave = tid >> 6;
    const int lane = tid & 63;
    const int n0   = blockIdx.x * 16;
    {
        const int d4 = lane * 4;
        const float invK = 1.0f / (float)KNEI;
#pragma unroll
        for (int i = 0; i < 4; ++i) {
            const int li = wave * 4 + i;
            const int n  = n0 + li;
#pragma unroll
            for (int r = 0; r < NREL; ++r) {
                const int* idxp = neigh_idx + ((size_t)r * NNODES + n) * KNEI;
                const float* tab = tables_to + (size_t)r * NTOTAL * DIM;
                float4 acc = make_float4(0.f, 0.f, 0.f, 0.f);
#pragma unroll 5
                for (int j = 0; j < KNEI; ++j) {
                    const float4 v = *(const float4*)(tab + (size_t)idxp[j] * DIM + d4);
                    acc.x += v.x; acc.y += v.y; acc.z += v.z; acc.w += v.w;
                }
                ushort4 pk;
                pk.x = f2bf(acc.x * invK); pk.y = f2bf(acc.y * invK);
                pk.z = f2bf(acc.z * invK); pk.w = f2bf(acc.w * invK);
                *(ushort4*)&Gt[li * GSTRIDE + r * 256 + d4] = pk;
            }
            {
                const float4 v = *(const float4*)(table_self + (size_t)nodes[n] * DIM + d4);
                ushort4 pk;
                pk.x = f2bf(v.x); pk.y = f2bf(v.y);
                pk.z = f2bf(v.z); pk.w = f2bf(v.w);
                *(ushort4*)&Gt[li * GSTRIDE + 3 * 256 + d4] = pk;
            }
        }
    }
    __syncthreads();
    const int quad = lane >> 4;
    const int l16  = lane & 15;
    f32x4 acc[4];
#pragma unroll
    for (int ct = 0; ct < 4; ++ct) acc[ct] = (f32x4){0.f, 0.f, 0.f, 0.f};
    for (int k0 = 0; k0 < 1024; k0 += 32) {
        const short8 a = *(const short8*)&Gt[l16 * GSTRIDE + k0 + quad * 8];
#pragma unroll
        for (int ct = 0; ct < 4; ++ct) {
            const int o = wave * 64 + ct * 16 + l16;
            const short8 b = *(const short8*)(M + (size_t)o * 1024 + k0 + quad * 8);
            acc[ct] = __builtin_amdgcn_mfma_f32_16x16x32_bf16(a, b, acc[ct], 0, 0, 0);
        }
    }
    const size_t orow0 = (size_t)blockIdx.x * 2;
#pragma unroll
    for (int ct = 0; ct < 4; ++ct) {
        float s = fmaxf(acc[ct][0], 0.f) + fmaxf(acc[ct][1], 0.f)
                + fmaxf(acc[ct][2], 0.f) + fmaxf(acc[ct][3], 0.f);
        s += __shfl_xor(s, 16, 64);
        s *= 0.125f;
        const int col = wave * 64 + ct * 16 + l16;
        if (quad == 0)      out[orow0 * 256 + col]       = s;
        else if (quad == 2) out[(orow0 + 1) * 256 + col] = s;
    }
}

extern "C" void kernel_launch(void* const* d_in, const int* in_sizes, int n_in,
                              void* d_out, int out_size, void* d_ws, size_t ws_size,
                              hipStream_t stream) {
    const int*   nodes  = (const int*)  d_in[0];
    const int*   neigh  = (const int*)  d_in[1];
    const float* tself  = (const float*)d_in[2];
    const float* tto    = (const float*)d_in[3];
    const float* wself  = (const float*)d_in[4];
    const float* wrel   = (const float*)d_in[5];
    const float* wcomp  = (const float*)d_in[6];
    float* outp = (float*)d_out;

    unsigned short* M = (unsigned short*)d_ws;              // 512 KB
    const size_t g_off  = 1u << 20;                         // 1 MB aligned
    const size_t g_size = (size_t)NNODES * 1024 * 2;        // 32 MB
    prep_M<<<256, 256, 0, stream>>>(wself, wrel, wcomp, M);
    if (ws_size >= g_off + g_size) {
        unsigned short* G = (unsigned short*)((char*)d_ws + g_off);
        gather_kernel<<<4096, 256, 0, stream>>>(nodes, neigh, tself, tto, G);
        gemm_kernel<<<1024, 256, 0, stream>>>(G, M, outp);
    } else {
        encoder_main<<<1024, 256, 0, stream>>>(nodes, neigh, tself, tto, M, outp);
    }
}